// Round 3
// baseline (629.079 us; speedup 1.0000x reference)
//
#include <hip/hip_runtime.h>
#include <hip/hip_bf16.h>

typedef unsigned short u16;
typedef unsigned int u32;
typedef __attribute__((ext_vector_type(8))) short short8;
typedef __attribute__((ext_vector_type(4))) float f32x4;

#define BATCH 8192
#define FEAT 512
#define DEG 32
#define BM 128
#define BN 128
#define BK 32

__device__ __forceinline__ u16 f2b(float f){
  __hip_bfloat16 h = __float2bfloat16(f);
  return *reinterpret_cast<u16*>(&h);
}
__device__ __forceinline__ u32 pack2(float lo, float hi){
  return (u32)f2b(lo) | (((u32)f2b(hi)) << 16);
}

__device__ __forceinline__ f32x4 mfma_bf16_16x16x32(short8 a, short8 b, f32x4 c){
  asm("v_mfma_f32_16x16x32_bf16 %0, %1, %2, %0" : "+v"(c) : "v"(a), "v"(b));
  return c;
}

// async global->LDS, 16B per lane; LDS dest = wave-uniform base + lane*16
__device__ __forceinline__ void gload16(const u16* g, u16* l){
  __builtin_amdgcn_global_load_lds(
      (const __attribute__((address_space(1))) u32*)(const void*)g,
      (__attribute__((address_space(3))) u32*)(void*)l, 16, 0, 0);
}

// ---- gather + mean-pool: agg(f32), cat=[self|agg](bf16), env(bf16) ----
// float4 path: 2 batch rows per block, 16B/lane loads (G13)
__global__ __launch_bounds__(256) void gather_agg(
    const float* __restrict__ feat, const int* __restrict__ nidx,
    float* __restrict__ out_agg, u16* __restrict__ cat_bf, u16* __restrict__ env_bf)
{
  const int t = threadIdx.x;
  const int half = t >> 7, tl = t & 127;
  const int b = blockIdx.x * 2 + half;
  __shared__ int idx[2][DEG];
  if (t < 2 * DEG)
    idx[t >> 5][t & 31] = nidx[(size_t)(blockIdx.x * 2 + (t >> 5)) * DEG + (t & 31)];
  __syncthreads();
  const int f = tl * 4;
  // neigh_idx[:,0] == nodes (self), so row k=0 doubles as the self row
  const float4 sv = *(const float4*)(feat + (size_t)idx[half][0] * FEAT + f);
  float4 s = sv;
  #pragma unroll 8
  for (int k = 1; k < DEG; ++k){
    const float4 v = *(const float4*)(feat + (size_t)idx[half][k] * FEAT + f);
    s.x += v.x; s.y += v.y; s.z += v.z; s.w += v.w;
  }
  const float4 a = make_float4(s.x*(1.f/32.f), s.y*(1.f/32.f), s.z*(1.f/32.f), s.w*(1.f/32.f));
  const float4 e = make_float4((s.x-sv.x)*(1.f/31.f), (s.y-sv.y)*(1.f/31.f),
                               (s.z-sv.z)*(1.f/31.f), (s.w-sv.w)*(1.f/31.f));
  *(float4*)(out_agg + (size_t)b * FEAT + f) = a;
  *(uint2*)(cat_bf + (size_t)b * 1024 + f)        = make_uint2(pack2(sv.x, sv.y), pack2(sv.z, sv.w));
  *(uint2*)(cat_bf + (size_t)b * 1024 + FEAT + f) = make_uint2(pack2(a.x, a.y), pack2(a.z, a.w));
  *(uint2*)(env_bf + (size_t)b * FEAT + f)        = make_uint2(pack2(e.x, e.y), pack2(e.z, e.w));
}

// ---------------- f32 -> bf16 transpose (out[c][r] = bf16(in[r][c])) --------
__global__ __launch_bounds__(256) void transpose_f2b(
    const float* __restrict__ in, u16* __restrict__ out, int R, int C)
{
  __shared__ float tile[32][33];
  const int c0 = blockIdx.x * 32, r0 = blockIdx.y * 32;
  const int x = threadIdx.x, y = threadIdx.y;
  #pragma unroll
  for (int i = 0; i < 32; i += 8)
    tile[y + i][x] = in[(size_t)(r0 + y + i) * C + (c0 + x)];
  __syncthreads();
  #pragma unroll
  for (int i = 0; i < 32; i += 8)
    out[(size_t)(c0 + y + i) * R + (r0 + x)] = f2b(tile[x][y + i]);
}

// ---- m97-style GEMM body: C[m][n] = sum_k A[m][k]*BT[n][k], bf16 in f32 out ----
// known-good 598us core: 128x128 tile, 4 waves, 2 __syncthreads per K-step
template<bool WRITE_RAW>
__device__ __forceinline__ void gemm_body(
    const u16* __restrict__ A, int lda, const u16* __restrict__ BT, int ldb,
    int K, float* __restrict__ Craw, float* __restrict__ Crelu, int ldc,
    int m0, int n0, u16* As, u16* Bs)
{
  const int t = threadIdx.x;
  const int wave = t >> 6, lane = t & 63;
  const int wr = wave >> 1, wc = wave & 1;
  const int lm = lane & 15, quad = lane >> 4;

  // staging coords: wave wv covers rows wv*32+(lane/4) (+16 for 2nd inst), col (lane%4)*8
  const int sr = wave * 32 + (lane >> 2);
  const int sc = (lane & 3) * 8;

  f32x4 acc[4][4] = {};

  for (int k0 = 0; k0 < K; k0 += BK){
    gload16(A  + (size_t)(m0 + sr)      * lda + k0 + sc, As + sr * 32 + sc);
    gload16(A  + (size_t)(m0 + sr + 16) * lda + k0 + sc, As + (sr + 16) * 32 + sc);
    gload16(BT + (size_t)(n0 + sr)      * ldb + k0 + sc, Bs + sr * 32 + sc);
    gload16(BT + (size_t)(n0 + sr + 16) * ldb + k0 + sc, Bs + (sr + 16) * 32 + sc);
    __syncthreads();
    short8 af[4], bf[4];
    #pragma unroll
    for (int i = 0; i < 4; ++i)
      af[i] = *(const short8*)&As[(wr * 64 + i * 16 + lm) * 32 + quad * 8];
    #pragma unroll
    for (int j = 0; j < 4; ++j)
      bf[j] = *(const short8*)&Bs[(wc * 64 + j * 16 + lm) * 32 + quad * 8];
    #pragma unroll
    for (int i = 0; i < 4; ++i)
      #pragma unroll
      for (int j = 0; j < 4; ++j)
        acc[i][j] = mfma_bf16_16x16x32(af[i], bf[j], acc[i][j]);
    __syncthreads();
  }
  #pragma unroll
  for (int i = 0; i < 4; ++i){
    const int row = m0 + wr * 64 + i * 16 + quad * 4;
    #pragma unroll
    for (int j = 0; j < 4; ++j){
      const int col = n0 + wc * 64 + j * 16 + lm;
      #pragma unroll
      for (int r = 0; r < 4; ++r){
        const float v = acc[i][j][r];
        const size_t off = (size_t)(row + r) * ldc + col;
        if (WRITE_RAW) Craw[off] = v;
        Crelu[off] = fmaxf(v, 0.f);
      }
    }
  }
}

// GEMM1 (z=0): cat @ Wgen -> raw, gen.  GEMM2 (z=1): env @ Wgen[512:] -> envraw, envgen.
__global__ __launch_bounds__(256) void gemm12(
    const u16* __restrict__ catA, const u16* __restrict__ envA,
    const u16* __restrict__ wgT,
    float* __restrict__ raw, float* __restrict__ gen,
    float* __restrict__ envraw, float* __restrict__ envgen)
{
  __shared__ __align__(16) u16 As[BM * BK];
  __shared__ __align__(16) u16 Bs[BN * BK];
  const int z = blockIdx.z;
  const u16* A  = z ? envA : catA;
  const int lda = z ? 512 : 1024;
  const int K   = z ? 512 : 1024;
  const u16* BT = z ? wgT + 512 : wgT;
  float* Craw   = z ? envraw : raw;
  float* Crelu  = z ? envgen : gen;
  gemm_body<true>(A, lda, BT, 1024, K, Craw, Crelu, 1024,
                  blockIdx.y * BM, blockIdx.x * BN, As, Bs);
}

// GEMM3: bnA @ weight1 -> relu only
__global__ __launch_bounds__(256) void gemm3(
    const u16* __restrict__ bnA, const u16* __restrict__ w1T,
    float* __restrict__ to_out)
{
  __shared__ __align__(16) u16 As[BM * BK];
  __shared__ __align__(16) u16 Bs[BN * BK];
  gemm_body<false>(bnA, 1536, w1T, 1536, 1536, nullptr, to_out, 1536,
                   blockIdx.y * BM, blockIdx.x * BN, As, Bs);
}

// ---------------- BN stats: atomic-free slab partials ----------------
// grid (6, 8): block owns 256 cols (float4/thread), slab = 1024 rows
__global__ __launch_bounds__(256) void bn_partial(
    const float* __restrict__ agg, const float* __restrict__ gen,
    float* __restrict__ partials)
{
  const int tq = threadIdx.x & 63, ty = threadIdx.x >> 6;
  const int c = blockIdx.x * 256 + tq * 4;      // block-uniform branch below
  const int r0 = blockIdx.y * 1024;
  float4 s = make_float4(0.f,0.f,0.f,0.f), q = make_float4(0.f,0.f,0.f,0.f);
  if (c < 512){
    for (int r = r0 + ty; r < r0 + 1024; r += 4){
      const float4 x = *(const float4*)(agg + (size_t)r * 512 + c);
      s.x += x.x; s.y += x.y; s.z += x.z; s.w += x.w;
      q.x += x.x*x.x; q.y += x.y*x.y; q.z += x.z*x.z; q.w += x.w*x.w;
    }
  } else {
    for (int r = r0 + ty; r < r0 + 1024; r += 4){
      const float4 x = *(const float4*)(gen + (size_t)r * 1024 + (c - 512));
      s.x += x.x; s.y += x.y; s.z += x.z; s.w += x.w;
      q.x += x.x*x.x; q.y += x.y*x.y; q.z += x.z*x.z; q.w += x.w*x.w;
    }
  }
  __shared__ float4 sh[2][4][64];
  sh[0][ty][tq] = s; sh[1][ty][tq] = q;
  __syncthreads();
  if (ty == 0){
    float4 s0 = sh[0][0][tq], s1 = sh[0][1][tq], s2 = sh[0][2][tq], s3 = sh[0][3][tq];
    float4 q0 = sh[1][0][tq], q1 = sh[1][1][tq], q2 = sh[1][2][tq], q3 = sh[1][3][tq];
    const float4 S = make_float4(s0.x+s1.x+s2.x+s3.x, s0.y+s1.y+s2.y+s3.y,
                                 s0.z+s1.z+s2.z+s3.z, s0.w+s1.w+s2.w+s3.w);
    const float4 Q = make_float4(q0.x+q1.x+q2.x+q3.x, q0.y+q1.y+q2.y+q3.y,
                                 q0.z+q1.z+q2.z+q3.z, q0.w+q1.w+q2.w+q3.w);
    *(float4*)(partials + (size_t)blockIdx.y * 3072 + c)        = S;
    *(float4*)(partials + (size_t)blockIdx.y * 3072 + 1536 + c) = Q;
  }
}

// ---- materialize BN-folded GEMM3 A-matrix with inline finalize ----
// bnA[m][c] = bf16(x*sc + tc); sc/tc computed per-thread from L2-resident partials
__global__ __launch_bounds__(384) void prep_bnA(
    const float* __restrict__ agg, const float* __restrict__ gen,
    const float* __restrict__ partials, const float* __restrict__ gamma,
    const float* __restrict__ beta, u16* __restrict__ bnA)
{
  const int m = blockIdx.x;
  const int t = threadIdx.x;       // 0..383
  const int c = t * 4;
  // inline bn_finalize: sum the 8 slab partials for these 4 cols
  float4 s = make_float4(0.f,0.f,0.f,0.f), q = make_float4(0.f,0.f,0.f,0.f);
  #pragma unroll
  for (int k = 0; k < 8; ++k){
    const float4 sk = *(const float4*)(partials + (size_t)k * 3072 + c);
    const float4 qk = *(const float4*)(partials + (size_t)k * 3072 + 1536 + c);
    s.x += sk.x; s.y += sk.y; s.z += sk.z; s.w += sk.w;
    q.x += qk.x; q.y += qk.y; q.z += qk.z; q.w += qk.w;
  }
  const float4 g4 = *(const float4*)(gamma + c);
  const float4 b4 = *(const float4*)(beta + c);
  float sc[4], tc[4];
  {
    const float mean0 = s.x*(1.f/8192.f), var0 = q.x*(1.f/8192.f) - mean0*mean0;
    const float mean1 = s.y*(1.f/8192.f), var1 = q.y*(1.f/8192.f) - mean1*mean1;
    const float mean2 = s.z*(1.f/8192.f), var2 = q.z*(1.f/8192.f) - mean2*mean2;
    const float mean3 = s.w*(1.f/8192.f), var3 = q.w*(1.f/8192.f) - mean3*mean3;
    sc[0] = g4.x * rsqrtf(var0 + 1e-5f); tc[0] = b4.x - mean0 * sc[0];
    sc[1] = g4.y * rsqrtf(var1 + 1e-5f); tc[1] = b4.y - mean1 * sc[1];
    sc[2] = g4.z * rsqrtf(var2 + 1e-5f); tc[2] = b4.z - mean2 * sc[2];
    sc[3] = g4.w * rsqrtf(var3 + 1e-5f); tc[3] = b4.w - mean3 * sc[3];
  }
  const float4 x = (c < 512)
      ? *(const float4*)(agg + (size_t)m * 512 + c)
      : *(const float4*)(gen + (size_t)m * 1024 + (c - 512));
  const u32 lo = pack2(fmaf(x.x, sc[0], tc[0]), fmaf(x.y, sc[1], tc[1]));
  const u32 hi = pack2(fmaf(x.z, sc[2], tc[2]), fmaf(x.w, sc[3], tc[3]));
  *(uint2*)(bnA + (size_t)m * 1536 + c) = make_uint2(lo, hi);
}

extern "C" void kernel_launch(void* const* d_in, const int* in_sizes, int n_in,
                              void* d_out, int out_size, void* d_ws, size_t ws_size,
                              hipStream_t stream)
{
  const float* feat  = (const float*)d_in[0];
  const float* Wgen  = (const float*)d_in[1];
  const float* W1    = (const float*)d_in[2];
  const float* gamma = (const float*)d_in[3];
  const float* beta  = (const float*)d_in[4];
  const int* nidx    = (const int*)d_in[6];

  float* o = (float*)d_out;
  float* out_agg    = o;                // [8192,512]
  float* out_to     = o + 4194304;      // [8192,1536]
  float* out_gen    = o + 16777216;     // [8192,1024]
  float* out_raw    = o + 25165824;     // [8192,1024]
  float* out_envgen = o + 33554432;     // [8192,1024]
  float* out_envraw = o + 41943040;     // [8192,1024]

  // ws: 30.5 MB; partials overlays wgT (dead after gemm12); bnA overlays cat+env
  char* w = (char*)d_ws;
  u16* wgT    = (u16*)(w + 32768);           // 2 MB    [1024,1024] bf16 W_gen^T
  float* partials = (float*)(w + 32768);     // 96 KB overlay (8 slabs x 3072)
  u16* w1T    = (u16*)(w + 2129920);         // 4.5 MB  [1536,1536] bf16 weight1^T
  u16* cat_bf = (u16*)(w + 6848512);         // 16.8 MB [8192,1024] bf16 [self|agg]
  u16* env_bf = (u16*)(w + 23625728);        // 8.4 MB  [8192,512]  bf16 env
  u16* bnA_bf = (u16*)(w + 6848512);         // 25.2 MB [8192,1536] overlay
  // end: 32,014,336 bytes

  gather_agg<<<BATCH / 2, 256, 0, stream>>>(feat, nidx, out_agg, cat_bf, env_bf);
  transpose_f2b<<<dim3(32, 32), dim3(32, 8), 0, stream>>>(Wgen, wgT, 1024, 1024);
  transpose_f2b<<<dim3(48, 48), dim3(32, 8), 0, stream>>>(W1, w1T, 1536, 1536);

  // GEMM1+GEMM2 fused across blockIdx.z (1024 blocks -> 4/CU)
  gemm12<<<dim3(8, 64, 2), 256, 0, stream>>>(
      cat_bf, env_bf, wgT, out_raw, out_gen, out_envraw, out_envgen);

  bn_partial<<<dim3(6, 8), 256, 0, stream>>>(out_agg, out_gen, partials);
  prep_bnA<<<BATCH, 384, 0, stream>>>(out_agg, out_gen, partials, gamma, beta, bnA_bf);

  gemm3<<<dim3(12, 64), 256, 0, stream>>>(bnA_bf, w1T, out_to);
}